// Round 4
// baseline (490.260 us; speedup 1.0000x reference)
//
#include <hip/hip_runtime.h>
#include <math.h>

#define T_TOK 16384
#define D_DIM 4096
#define E_EXP 64

// d_out layout (float32): logits [T,64] | weights [T,2] | indices [T,2] | mask [64,2,T]
#define OFF_W   (T_TOK * E_EXP)
#define OFF_I   (OFF_W + T_TOK * 2)
#define OFF_M   (OFF_I + T_TOK * 2)

#define NCHUNK    64      // K chunks of 64 dims
#define CH_HALVES 4096    // 64x64 f16 per chunk (frag-major: 8 frags x 512)

typedef _Float16 half8 __attribute__((ext_vector_type(8)));
typedef float    f32x4 __attribute__((ext_vector_type(4)));

// ---------------------------------------------------------------------------
// prep: w [64][4096] fp32 -> ws_hi / ws_lo(x2^11) f16, frag-major per K-chunk.
// lane = n + 16*q holds B[n][q*8+j]; half offset =
//   chunk*4096 + (n_tile*2 + s)*512 + (n + 16*q)*8 + j,  k = s*32 + q*8 + j.
// (verified correct in round 3)
// ---------------------------------------------------------------------------
__global__ __launch_bounds__(256) void prep_w(const float* __restrict__ w,
                                              _Float16* __restrict__ ws_hi,
                                              _Float16* __restrict__ ws_lo) {
  const int g   = blockIdx.x * 256 + threadIdx.x;  // 0..16383
  const int exp = g >> 8;
  const int kb  = (g & 255) * 16;
  const float* src = w + (size_t)exp * D_DIM + kb;
  float vals[16];
#pragma unroll
  for (int i = 0; i < 4; i++) {
    const float4 f = *(const float4*)(src + i * 4);
    vals[i * 4 + 0] = f.x; vals[i * 4 + 1] = f.y;
    vals[i * 4 + 2] = f.z; vals[i * 4 + 3] = f.w;
  }
  const int n_tile = exp >> 4, nn = exp & 15;
#pragma unroll
  for (int part = 0; part < 2; part++) {
    const int k0 = kb + part * 8;
    const int c = k0 >> 6, rem = k0 & 63;
    const int s = rem >> 5, q = (rem >> 3) & 3;
    const size_t off = (size_t)c * CH_HALVES + (n_tile * 2 + s) * 512 + (nn + 16 * q) * 8;
    half8 hv, lv;
#pragma unroll
    for (int j = 0; j < 8; j++) {
      const float xf = vals[part * 8 + j];
      const _Float16 h = (_Float16)xf;            // RNE
      hv[j] = h;
      lv[j] = (_Float16)((xf - (float)h) * 2048.0f);
    }
    *(half8*)(ws_hi + off) = hv;
    *(half8*)(ws_lo + off) = lv;
  }
}

// ---------------------------------------------------------------------------
// main: 256 blocks x 256 thr, NO LDS, NO BARRIERS. Each wave independently
// computes 16 tokens x 64 experts. A-frags loaded straight from x (fp32) and
// split to f16 hi/lo in-register; B-frags loaded straight from frag-major ws.
// 4-deep A prefetch, 2-deep B prefetch. Fused top-2 router epilogue.
// ---------------------------------------------------------------------------
__global__ __launch_bounds__(256) void moe_mfma(
    const float* __restrict__ x, const _Float16* __restrict__ ws_hi,
    const _Float16* __restrict__ ws_lo, const float* __restrict__ bias,
    float* __restrict__ out) {
  const int tid  = threadIdx.x;
  const int wave = tid >> 6;
  const int lane = tid & 63;
  const int m    = lane & 15;     // token-in-wave (A row, C col index source)
  const int q    = lane >> 4;     // k-oct selector / C row group
  const int trowbase = blockIdx.x * 64 + wave * 16;
  const float* xrow = x + (size_t)(trowbase + m) * D_DIM + q * 8;

  f32x4 accm[4], accc[4];
#pragma unroll
  for (int t = 0; t < 4; t++) {
    accm[t] = (f32x4){0.f, 0.f, 0.f, 0.f};
    accc[t] = (f32x4){0.f, 0.f, 0.f, 0.f};
  }

  float4 abuf[4][2];          // 4-deep A prefetch (8 fp32 each)
  uint4  bh[2][4], bl[2][4];  // 2-deep B prefetch (4 n-tiles, hi+lo)

  auto aload = [&](int ks, int slot) {
    const float* p = xrow + (ks >> 1) * 64 + (ks & 1) * 32;
    abuf[slot][0] = *(const float4*)p;
    abuf[slot][1] = *(const float4*)(p + 4);
  };
  auto bload = [&](int ks, int pb) {
    const size_t base = (size_t)(ks >> 1) * CH_HALVES + (ks & 1) * 512 + lane * 8;
    const _Float16* ph = ws_hi + base;
    const _Float16* pl = ws_lo + base;
#pragma unroll
    for (int t = 0; t < 4; t++) {
      bh[pb][t] = *(const uint4*)(ph + t * 1024);
      bl[pb][t] = *(const uint4*)(pl + t * 1024);
    }
  };
  auto comp = [&](int slot, int pb) {
    const float4 f0 = abuf[slot][0], f1 = abuf[slot][1];
    const float vv[8] = {f0.x, f0.y, f0.z, f0.w, f1.x, f1.y, f1.z, f1.w};
    half8 ah, al;
#pragma unroll
    for (int j = 0; j < 8; j++) {
      const _Float16 h = (_Float16)vv[j];
      ah[j] = h;
      al[j] = (_Float16)((vv[j] - (float)h) * 2048.0f);
    }
#pragma unroll
    for (int t = 0; t < 4; t++) {
      const half8 bhv = *(const half8*)&bh[pb][t];
      const half8 blv = *(const half8*)&bl[pb][t];
      accm[t] = __builtin_amdgcn_mfma_f32_16x16x32_f16(ah, bhv, accm[t], 0, 0, 0);
      accc[t] = __builtin_amdgcn_mfma_f32_16x16x32_f16(ah, blv, accc[t], 0, 0, 0);
      accc[t] = __builtin_amdgcn_mfma_f32_16x16x32_f16(al, bhv, accc[t], 0, 0, 0);
    }
  };

  // prologue
  aload(0, 0); aload(1, 1); aload(2, 2); aload(3, 3);
  bload(0, 0); bload(1, 1);

#pragma unroll 1
  for (int ks = 0; ks < 128; ks += 2) {
    comp(ks & 3, 0);
    if (ks + 4 < 128) aload(ks + 4, (ks + 4) & 3);  // same slot just consumed
    if (ks + 2 < 128) bload(ks + 2, 0);
    comp((ks + 1) & 3, 1);
    if (ks + 5 < 128) aload(ks + 5, (ks + 5) & 3);
    if (ks + 3 < 128) bload(ks + 3, 1);
  }

  // ---- epilogue: combine, bias, write logits ----------------------------
  // C/D layout: col = lane&15 (expert-in-tile), row = (lane>>4)*4 + reg (token)
  const int cc = lane & 15;
  float fin[4][4];
#pragma unroll
  for (int t = 0; t < 4; t++) {
    const float bb = bias[t * 16 + cc];
#pragma unroll
    for (int r = 0; r < 4; r++)
      fin[t][r] = accm[t][r] + accc[t][r] * 4.8828125e-4f + bb;  // 2^-11
  }
#pragma unroll
  for (int r = 0; r < 4; r++) {
    const int trow = trowbase + q * 4 + r;
#pragma unroll
    for (int t = 0; t < 4; t++)
      out[(size_t)trow * E_EXP + t * 16 + cc] = fin[t][r];
  }

  // ---- fused router: top-2 across 16 lanes (butterfly) ------------------
#pragma unroll
  for (int r = 0; r < 4; r++) {
    float v1 = fin[0][r]; int i1 = cc;
    float v2 = -3.4e38f;  int i2 = 0;
#pragma unroll
    for (int t = 1; t < 4; t++) {
      const float vc = fin[t][r]; const int ic = t * 16 + cc;
      if (vc > v1)      { v2 = v1; i2 = i1; v1 = vc; i1 = ic; }
      else if (vc > v2) { v2 = vc; i2 = ic; }
    }
#pragma unroll
    for (int mk = 1; mk <= 8; mk <<= 1) {
      const float ov1 = __shfl_xor(v1, mk); const int oi1 = __shfl_xor(i1, mk);
      const float ov2 = __shfl_xor(v2, mk); const int oi2 = __shfl_xor(i2, mk);
      if ((ov1 > v1) || (ov1 == v1 && oi1 < i1)) {
        const bool s2 = (v1 > ov2) || (v1 == ov2 && i1 < oi2);
        v2 = s2 ? v1 : ov2; i2 = s2 ? i1 : oi2;
        v1 = ov1; i1 = oi1;
      } else {
        const bool s2 = (ov1 > v2) || (ov1 == v2 && oi1 < i2);
        v2 = s2 ? ov1 : v2; i2 = s2 ? oi1 : i2;
      }
    }
    if (cc == 0) {
      const int trow = trowbase + q * 4 + r;
      const float d  = expf(v2 - v1);
      const float w1 = 1.f / (1.f + d);
      out[OFF_W + trow * 2 + 0] = w1;
      out[OFF_W + trow * 2 + 1] = d * w1;
      out[OFF_I + trow * 2 + 0] = (float)i1;
      out[OFF_I + trow * 2 + 1] = (float)i2;
      out[OFF_M + (size_t)(i1 * 2 + 0) * T_TOK + trow] = 1.0f;
      out[OFF_M + (size_t)(i2 * 2 + 1) * T_TOK + trow] = 1.0f;
    }
  }
}

extern "C" void kernel_launch(void* const* d_in, const int* in_sizes, int n_in,
                              void* d_out, int out_size, void* d_ws, size_t ws_size,
                              hipStream_t stream) {
  const float* x    = (const float*)d_in[0];
  const float* w    = (const float*)d_in[1];
  const float* bias = (const float*)d_in[2];
  float* out = (float*)d_out;
  _Float16* ws_hi = (_Float16*)d_ws;
  _Float16* ws_lo = ws_hi + (size_t)NCHUNK * CH_HALVES;  // +512 KB

  hipMemsetAsync(out + OFF_M, 0, (size_t)E_EXP * 2 * T_TOK * sizeof(float), stream);
  prep_w<<<E_EXP * D_DIM / (256 * 16), 256, 0, stream>>>(w, ws_hi, ws_lo);
  moe_mfma<<<T_TOK / 64, 256, 0, stream>>>(x, ws_hi, ws_lo, bias, out);
}

// Round 5
// 399.355 us; speedup vs baseline: 1.2276x; 1.2276x over previous
//
#include <hip/hip_runtime.h>
#include <math.h>

#define T_TOK 16384
#define D_DIM 4096
#define E_EXP 64

// d_out layout (float32): logits [T,64] | weights [T,2] | indices [T,2] | mask [64,2,T]
#define OFF_W   (T_TOK * E_EXP)
#define OFF_I   (OFF_W + T_TOK * 2)
#define OFF_M   (OFF_I + T_TOK * 2)

#define NCHUNK    64      // K chunks of 64 dims
#define CH_HALVES 4096    // 64x64 f16 per chunk (frag-major: 8 frags x 512)

typedef _Float16 half8 __attribute__((ext_vector_type(8)));
typedef float    f32x4 __attribute__((ext_vector_type(4)));

// ---------------------------------------------------------------------------
// prep: w [64][4096] fp32 -> ws_hi / ws_lo(x2^11) f16, frag-major per K-chunk.
// lane = n + 16*q holds B[n][q*8+j]; half offset =
//   chunk*4096 + (n_tile*2 + s)*512 + (n + 16*q)*8 + j,  k = s*32 + q*8 + j.
// (verified correct rounds 3-4)
// ---------------------------------------------------------------------------
__global__ __launch_bounds__(256) void prep_w(const float* __restrict__ w,
                                              _Float16* __restrict__ ws_hi,
                                              _Float16* __restrict__ ws_lo) {
  const int g   = blockIdx.x * 256 + threadIdx.x;  // 0..16383
  const int exp = g >> 8;
  const int kb  = (g & 255) * 16;
  const float* src = w + (size_t)exp * D_DIM + kb;
  float vals[16];
#pragma unroll
  for (int i = 0; i < 4; i++) {
    const float4 f = *(const float4*)(src + i * 4);
    vals[i * 4 + 0] = f.x; vals[i * 4 + 1] = f.y;
    vals[i * 4 + 2] = f.z; vals[i * 4 + 3] = f.w;
  }
  const int n_tile = exp >> 4, nn = exp & 15;
#pragma unroll
  for (int part = 0; part < 2; part++) {
    const int k0 = kb + part * 8;
    const int c = k0 >> 6, rem = k0 & 63;
    const int s = rem >> 5, q = (rem >> 3) & 3;
    const size_t off = (size_t)c * CH_HALVES + (n_tile * 2 + s) * 512 + (nn + 16 * q) * 8;
    half8 hv, lv;
#pragma unroll
    for (int j = 0; j < 8; j++) {
      const float xf = vals[part * 8 + j];
      const _Float16 h = (_Float16)xf;            // RNE
      hv[j] = h;
      lv[j] = (_Float16)((xf - (float)h) * 2048.0f);
    }
    *(half8*)(ws_hi + off) = hv;
    *(half8*)(ws_lo + off) = lv;
  }
}

// ---------------------------------------------------------------------------
// main: 256 blocks x 512 thr (8 waves). Barrier-free K-loop, 2-way K-split:
// wave wv: wg=wv&3 owns tokens [wg*16,+16), h=wv>>2 owns K-half h.
// All prefetch buffers constant-indexed (no dynamic reg-array indexing ->
// no scratch spill; round-4 failure mode). One LDS combine + barrier at end.
// ---------------------------------------------------------------------------
__global__ __launch_bounds__(512, 2) void moe_mfma(
    const float* __restrict__ x, const _Float16* __restrict__ ws_hi,
    const _Float16* __restrict__ ws_lo, const float* __restrict__ bias,
    float* __restrict__ out) {
  __shared__ float part[4 * 32 * 64];  // 32 KB: [wg][reg32][lane]

  const int tid  = threadIdx.x;
  const int wv   = tid >> 6;
  const int wg   = wv & 3;        // token group
  const int h    = wv >> 2;       // K-half
  const int lane = tid & 63;
  const int m    = lane & 15;     // token-in-wave
  const int q    = lane >> 4;     // k-oct / C row group
  const int trowbase = blockIdx.x * 64 + wg * 16;
  const float* xrow = x + (size_t)(trowbase + m) * D_DIM + q * 8;
  const int cbase = h * 32;       // 32 chunks per half

  f32x4 accm[4], accc[4];
#pragma unroll
  for (int t = 0; t < 4; t++) {
    accm[t] = (f32x4){0.f, 0.f, 0.f, 0.f};
    accc[t] = (f32x4){0.f, 0.f, 0.f, 0.f};
  }

  // double-buffered prefetch registers (ALL indices compile-time constant)
  float4 A0[4], A1[4];            // chunk A: [s*2 + half-of-8]
  half8  B0h[2][4], B0l[2][4];    // chunk B: [s][tile]
  half8  B1h[2][4], B1l[2][4];

#define LOADA(A, c_) do {                                                  \
    const float* p_ = xrow + (c_) * 64;                                    \
    A[0] = *(const float4*)(p_);      A[1] = *(const float4*)(p_ + 4);     \
    A[2] = *(const float4*)(p_ + 32); A[3] = *(const float4*)(p_ + 36);    \
  } while (0)

#define LOADB(Bh, Bl, c_) do {                                             \
    const _Float16* ph_ = ws_hi + (size_t)(c_) * CH_HALVES + lane * 8;     \
    const _Float16* pl_ = ws_lo + (size_t)(c_) * CH_HALVES + lane * 8;     \
    _Pragma("unroll") for (int s_ = 0; s_ < 2; s_++)                       \
    { _Pragma("unroll") for (int t_ = 0; t_ < 4; t_++) {                   \
        Bh[s_][t_] = *(const half8*)(ph_ + s_ * 512 + t_ * 1024);          \
        Bl[s_][t_] = *(const half8*)(pl_ + s_ * 512 + t_ * 1024);          \
    } }                                                                    \
  } while (0)

#define CVT8(ah_, al_, f0, f1) do {                                        \
    const float vv_[8] = {f0.x, f0.y, f0.z, f0.w, f1.x, f1.y, f1.z, f1.w}; \
    _Pragma("unroll") for (int j_ = 0; j_ < 8; j_++) {                     \
      const _Float16 hh_ = (_Float16)vv_[j_];                              \
      ah_[j_] = hh_;                                                       \
      al_[j_] = (_Float16)((vv_[j_] - (float)hh_) * 2048.0f);              \
    }                                                                      \
  } while (0)

#define COMP(A, Bh, Bl) do {                                               \
    half8 ah0_, al0_, ah1_, al1_;                                          \
    CVT8(ah0_, al0_, A[0], A[1]);                                          \
    CVT8(ah1_, al1_, A[2], A[3]);                                          \
    _Pragma("unroll") for (int t_ = 0; t_ < 4; t_++) {                     \
      accm[t_] = __builtin_amdgcn_mfma_f32_16x16x32_f16(ah0_, Bh[0][t_], accm[t_], 0, 0, 0); \
      accc[t_] = __builtin_amdgcn_mfma_f32_16x16x32_f16(ah0_, Bl[0][t_], accc[t_], 0, 0, 0); \
      accc[t_] = __builtin_amdgcn_mfma_f32_16x16x32_f16(al0_, Bh[0][t_], accc[t_], 0, 0, 0); \
    }                                                                      \
    _Pragma("unroll") for (int t_ = 0; t_ < 4; t_++) {                     \
      accm[t_] = __builtin_amdgcn_mfma_f32_16x16x32_f16(ah1_, Bh[1][t_], accm[t_], 0, 0, 0); \
      accc[t_] = __builtin_amdgcn_mfma_f32_16x16x32_f16(ah1_, Bl[1][t_], accc[t_], 0, 0, 0); \
      accc[t_] = __builtin_amdgcn_mfma_f32_16x16x32_f16(al1_, Bh[1][t_], accc[t_], 0, 0, 0); \
    }                                                                      \
  } while (0)

  LOADA(A0, cbase);     LOADB(B0h, B0l, cbase);
  LOADA(A1, cbase + 1); LOADB(B1h, B1l, cbase + 1);

#pragma unroll 1
  for (int c = cbase; c < cbase + 32; c += 2) {
    COMP(A0, B0h, B0l);
    if (c + 2 < cbase + 32) { LOADA(A0, c + 2); LOADB(B0h, B0l, c + 2); }
    COMP(A1, B1h, B1l);
    if (c + 3 < cbase + 32) { LOADA(A1, c + 3); LOADB(B1h, B1l, c + 3); }
  }

  // ---- K-split combine: h=1 waves deposit partials, h=0 waves reduce ----
  if (h == 1) {
    float* pp = part + wg * 2048 + lane;
#pragma unroll
    for (int t = 0; t < 4; t++)
#pragma unroll
      for (int r = 0; r < 4; r++) {
        pp[(t * 4 + r) * 64]        = accm[t][r];
        pp[(16 + t * 4 + r) * 64]   = accc[t][r];
      }
  }
  __syncthreads();
  if (h == 1) return;
  {
    const float* pp = part + wg * 2048 + lane;
#pragma unroll
    for (int t = 0; t < 4; t++)
#pragma unroll
      for (int r = 0; r < 4; r++) {
        accm[t][r] += pp[(t * 4 + r) * 64];
        accc[t][r] += pp[(16 + t * 4 + r) * 64];
      }
  }

  // ---- epilogue: combine hi/lo, bias, write logits ----------------------
  // C/D layout: col = lane&15 (expert-in-tile), row = (lane>>4)*4 + reg
  const int cc = m;
  float fin[4][4];
#pragma unroll
  for (int t = 0; t < 4; t++) {
    const float bb = bias[t * 16 + cc];
#pragma unroll
    for (int r = 0; r < 4; r++)
      fin[t][r] = accm[t][r] + accc[t][r] * 4.8828125e-4f + bb;  // 2^-11
  }
#pragma unroll
  for (int r = 0; r < 4; r++) {
    const int trow = trowbase + q * 4 + r;
#pragma unroll
    for (int t = 0; t < 4; t++)
      out[(size_t)trow * E_EXP + t * 16 + cc] = fin[t][r];
  }

  // ---- fused router: top-2 across 16 lanes (butterfly) ------------------
#pragma unroll
  for (int r = 0; r < 4; r++) {
    float v1 = fin[0][r]; int i1 = cc;
    float v2 = -3.4e38f;  int i2 = 0;
#pragma unroll
    for (int t = 1; t < 4; t++) {
      const float vc = fin[t][r]; const int ic = t * 16 + cc;
      if (vc > v1)      { v2 = v1; i2 = i1; v1 = vc; i1 = ic; }
      else if (vc > v2) { v2 = vc; i2 = ic; }
    }
#pragma unroll
    for (int mk = 1; mk <= 8; mk <<= 1) {
      const float ov1 = __shfl_xor(v1, mk); const int oi1 = __shfl_xor(i1, mk);
      const float ov2 = __shfl_xor(v2, mk); const int oi2 = __shfl_xor(i2, mk);
      if ((ov1 > v1) || (ov1 == v1 && oi1 < i1)) {
        const bool s2 = (v1 > ov2) || (v1 == ov2 && i1 < oi2);
        v2 = s2 ? v1 : ov2; i2 = s2 ? i1 : oi2;
        v1 = ov1; i1 = oi1;
      } else {
        const bool s2 = (ov1 > v2) || (ov1 == v2 && oi1 < i2);
        v2 = s2 ? ov1 : v2; i2 = s2 ? oi1 : i2;
      }
    }
    if (cc == 0) {
      const int trow = trowbase + q * 4 + r;
      const float d  = expf(v2 - v1);
      const float w1 = 1.f / (1.f + d);
      out[OFF_W + trow * 2 + 0] = w1;
      out[OFF_W + trow * 2 + 1] = d * w1;
      out[OFF_I + trow * 2 + 0] = (float)i1;
      out[OFF_I + trow * 2 + 1] = (float)i2;
      out[OFF_M + (size_t)(i1 * 2 + 0) * T_TOK + trow] = 1.0f;
      out[OFF_M + (size_t)(i2 * 2 + 1) * T_TOK + trow] = 1.0f;
    }
  }
}

extern "C" void kernel_launch(void* const* d_in, const int* in_sizes, int n_in,
                              void* d_out, int out_size, void* d_ws, size_t ws_size,
                              hipStream_t stream) {
  const float* x    = (const float*)d_in[0];
  const float* w    = (const float*)d_in[1];
  const float* bias = (const float*)d_in[2];
  float* out = (float*)d_out;
  _Float16* ws_hi = (_Float16*)d_ws;
  _Float16* ws_lo = ws_hi + (size_t)NCHUNK * CH_HALVES;  // +512 KB

  hipMemsetAsync(out + OFF_M, 0, (size_t)E_EXP * 2 * T_TOK * sizeof(float), stream);
  prep_w<<<E_EXP * D_DIM / (256 * 16), 256, 0, stream>>>(w, ws_hi, ws_lo);
  moe_mfma<<<T_TOK / 64, 512, 0, stream>>>(x, ws_hi, ws_lo, bias, out);
}